// Round 4
// baseline (364.340 us; speedup 1.0000x reference)
//
#include <hip/hip_runtime.h>

// ECE over N=32M samples, n_bins=10.
// Round 4: rounds 1-3 were scratch-bound (per-thread accumulator ARRAYS ->
// runtime-indexed alloca -> local memory; ~40 scratch ops/element, duration
// insensitive to L3 warmth, VGPR stuck at 32). This version uses staircase
// threshold sums with NAMED SCALARS ONLY (no arrays in the hot path):
//   C_j = #{v : b_j < v}  (ballot+popc -> SALU, wave-uniform)
//   A_j = sum ok*[b_j<v], T_j = sum v*[b_j<v]  (per-lane floats)
// Per-bin values recovered by differencing in the f64 finalize:
//   cnt_bin_j = C_j - C_{j+1} (C_0 = total, C_10 = 0), same for A, T.
// Binning is bit-exact vs jnp.linspace(0,1,11)[1:] + searchsorted(left):
// b_j = (float)j * 0.1f, compare strict b_j < v.

#define NBLK 2048
#define TPB  256
#define NTH  (NBLK * TPB)
#define MAXB 256

// one threshold: compare + SALU count + two masked float adds
#define SB(J)                                                   \
  { bool g = ((float)(J) * 0.1f) < v;                           \
    c##J += (unsigned)__popcll(__ballot(g));                    \
    a##J += g ? okf : 0.0f;                                     \
    t##J += g ? v : 0.0f; }

// one element slot (all lanes active or exec-masked prefix)
#define SLOT(cx, px, lx)                                        \
  { float v = (cx);                                             \
    float okf = ((px) == (lx)) ? 1.0f : 0.0f;                   \
    cAll += (unsigned)__popcll(__ballot(1));                    \
    tAll += v; aAll += okf;                                     \
    SB(1) SB(2) SB(3) SB(4) SB(5) SB(6) SB(7) SB(8) SB(9) }

#define WRED(x)                                                 \
  { x += __shfl_xor(x, 32, 64); x += __shfl_xor(x, 16, 64);     \
    x += __shfl_xor(x, 8, 64);  x += __shfl_xor(x, 4, 64);      \
    x += __shfl_xor(x, 2, 64);  x += __shfl_xor(x, 1, 64); }

__global__ __launch_bounds__(TPB) void ece_partial(
    const float* __restrict__ conf, const int* __restrict__ pred,
    const int* __restrict__ lab, const int* __restrict__ nbins_p,
    int n, int cap,
    float* __restrict__ ws_cnt, float* __restrict__ ws_acc,
    float* __restrict__ ws_conf)
{
  const int nb = nbins_p[0];
  const int tid = blockIdx.x * blockDim.x + threadIdx.x;
  const int lane = threadIdx.x & 63;
  const int wv   = threadIdx.x >> 6;

  __shared__ float l_c[TPB / 64][10];
  __shared__ float l_a[TPB / 64][10];
  __shared__ float l_t[TPB / 64][10];
  __shared__ unsigned g_cnt[MAXB];
  __shared__ unsigned g_acc[MAXB];
  __shared__ float    g_conf[MAXB];

  if (nb == 10 && cap >= 10) {
    // ---------------- fast path: staircase sums, named scalars only ----------------
    unsigned cAll = 0, c1 = 0, c2 = 0, c3 = 0, c4v = 0, c5 = 0, c6 = 0, c7 = 0, c8 = 0, c9 = 0;
    float aAll = 0.f, a1 = 0.f, a2 = 0.f, a3 = 0.f, a4 = 0.f, a5 = 0.f, a6 = 0.f, a7 = 0.f, a8 = 0.f, a9 = 0.f;
    float tAll = 0.f, t1 = 0.f, t2 = 0.f, t3 = 0.f, t4 = 0.f, t5 = 0.f, t6 = 0.f, t7 = 0.f, t8 = 0.f, t9 = 0.f;
    // rename c4v to avoid clash with pointer name below; macro uses c##J, so alias:
#define c4 c4v
    const int n4 = n >> 2;
    const float4* cp4 = (const float4*)conf;
    const int4*   pp4 = (const int4*)pred;
    const int4*   lp4 = (const int4*)lab;

    const int ITERS = (n4 + NTH - 1) / NTH;  // uniform trip count (wave-safe ballots)
    int idx = tid;
    for (int it = 0; it < ITERS; ++it, idx += NTH) {
      if (idx < n4) {  // boundary wave: active lanes form a prefix -> lane 0 valid
        float4 c = cp4[idx];
        int4   p = pp4[idx];
        int4   l = lp4[idx];
        SLOT(c.x, p.x, l.x)
        SLOT(c.y, p.y, l.y)
        SLOT(c.z, p.z, l.z)
        SLOT(c.w, p.w, l.w)
      }
    }
    // ragged tail (n % 4): one full-wave slot in block 0 / wave 0, validity-masked
    if (blockIdx.x == 0 && wv == 0) {
      const int base = n4 << 2;
      if (base < n) {
        int en  = base + lane;
        int enc = en < n ? en : (n - 1);
        float vr = conf[enc];
        int   pr = pred[enc];
        int   lr = lab[enc];
        bool vld = en < n;
        float v   = vld ? vr : 0.0f;
        float okf = (vld && pr == lr) ? 1.0f : 0.0f;
        cAll += (unsigned)__popcll(__ballot(vld));
        tAll += v; aAll += okf;
        SB(1) SB(2) SB(3) SB(4) SB(5) SB(6) SB(7) SB(8) SB(9)
      }
    }
#undef c4

    // wave-reduce the per-lane floats (counts are wave-uniform at lane 0 already)
    WRED(aAll) WRED(a1) WRED(a2) WRED(a3) WRED(a4) WRED(a5) WRED(a6) WRED(a7) WRED(a8) WRED(a9)
    WRED(tAll) WRED(t1) WRED(t2) WRED(t3) WRED(t4) WRED(t5) WRED(t6) WRED(t7) WRED(t8) WRED(t9)

    if (lane == 0) {
      l_c[wv][0] = (float)cAll; l_c[wv][1] = (float)c1; l_c[wv][2] = (float)c2;
      l_c[wv][3] = (float)c3;   l_c[wv][4] = (float)c4v; l_c[wv][5] = (float)c5;
      l_c[wv][6] = (float)c6;   l_c[wv][7] = (float)c7; l_c[wv][8] = (float)c8;
      l_c[wv][9] = (float)c9;
      l_a[wv][0] = aAll; l_a[wv][1] = a1; l_a[wv][2] = a2; l_a[wv][3] = a3;
      l_a[wv][4] = a4;   l_a[wv][5] = a5; l_a[wv][6] = a6; l_a[wv][7] = a7;
      l_a[wv][8] = a8;   l_a[wv][9] = a9;
      l_t[wv][0] = tAll; l_t[wv][1] = t1; l_t[wv][2] = t2; l_t[wv][3] = t3;
      l_t[wv][4] = t4;   l_t[wv][5] = t5; l_t[wv][6] = t6; l_t[wv][7] = t7;
      l_t[wv][8] = t8;   l_t[wv][9] = t9;
    }
    __syncthreads();
    if (threadIdx.x < 10) {
      float sc = 0.f, sa = 0.f, st = 0.f;
#pragma unroll
      for (int w = 0; w < TPB / 64; ++w) {
        sc += l_c[w][threadIdx.x];
        sa += l_a[w][threadIdx.x];
        st += l_t[w][threadIdx.x];
      }
      const int o = threadIdx.x * NBLK + blockIdx.x;  // [row][block]
      ws_cnt[o]  = sc;
      ws_acc[o]  = sa;
      ws_conf[o] = st;
    }
  } else {
    // ---------------- generic fallback: LDS-atomic privatized histogram ----------------
    int nbc = nb < 1 ? 1 : nb;
    if (nbc > MAXB) nbc = MAXB;
    if (nbc > cap) nbc = (cap < 1) ? 1 : cap;
    for (int j = threadIdx.x; j < nbc; j += blockDim.x) { g_cnt[j] = 0u; g_acc[j] = 0u; g_conf[j] = 0.0f; }
    __syncthreads();
    const float delta = 1.0f / (float)nb;
    for (int i = tid; i < n; i += NTH) {
      float v = conf[i];
      int okk = (pred[i] == lab[i]);
      int bin = (int)(v * (float)nb);
      if (bin > nb - 1) bin = nb - 1;
      if (bin < 0) bin = 0;
      while (bin < nb - 1 && (float)(bin + 1) * delta < v) ++bin;
      while (bin > 0 && !((float)bin * delta < v)) --bin;
      if (bin > nbc - 1) bin = nbc - 1;
      atomicAdd(&g_cnt[bin], 1u);
      atomicAdd(&g_acc[bin], (unsigned)okk);
      atomicAdd(&g_conf[bin], v);
    }
    __syncthreads();
    for (int j = threadIdx.x; j < nbc; j += blockDim.x) {
      ws_cnt[j * NBLK + blockIdx.x]  = (float)g_cnt[j];
      ws_acc[j * NBLK + blockIdx.x]  = (float)g_acc[j];
      ws_conf[j * NBLK + blockIdx.x] = g_conf[j];
    }
  }
}

__global__ __launch_bounds__(640) void ece_final(
    const float* __restrict__ ws_cnt, const float* __restrict__ ws_acc,
    const float* __restrict__ ws_conf, const int* __restrict__ nbins_p,
    int n, int cap, float* __restrict__ out)
{
  int nb = nbins_p[0];
  if (nb < 1) nb = 1;
  int mx = cap < MAXB ? cap : MAXB;
  if (nb > mx) nb = mx;
  const int wv   = threadIdx.x >> 6;
  const int lane = threadIdx.x & 63;
  __shared__ double C[MAXB], A[MAXB], T[MAXB];
  for (int j = threadIdx.x; j < MAXB; j += blockDim.x) { C[j] = 0.0; A[j] = 0.0; T[j] = 0.0; }
  __syncthreads();

  const int nrows = (nb == 10) ? 10 : nb;
  for (int row = wv; row < nrows; row += 10) {
    const float4* c4 = (const float4*)(ws_cnt  + (size_t)row * NBLK);
    const float4* a4 = (const float4*)(ws_acc  + (size_t)row * NBLK);
    const float4* t4 = (const float4*)(ws_conf + (size_t)row * NBLK);
    double sc = 0.0, sa = 0.0, st = 0.0;
#pragma unroll
    for (int itr = 0; itr < NBLK / 256; ++itr) {  // 8 iters of 64 lanes * float4
      float4 a = c4[itr * 64 + lane];
      float4 b = a4[itr * 64 + lane];
      float4 f = t4[itr * 64 + lane];
      sc += ((double)a.x + (double)a.y) + ((double)a.z + (double)a.w);
      sa += ((double)b.x + (double)b.y) + ((double)b.z + (double)b.w);
      st += ((double)f.x + (double)f.y) + ((double)f.z + (double)f.w);
    }
#pragma unroll
    for (int d = 32; d > 0; d >>= 1) {
      sc += __shfl_xor(sc, d, 64);
      sa += __shfl_xor(sa, d, 64);
      st += __shfl_xor(st, d, 64);
    }
    if (lane == 0) { C[row] = sc; A[row] = sa; T[row] = st; }
  }
  __syncthreads();
  if (threadIdx.x == 0) {
    double e = 0.0;
    if (nb == 10) {
      // staircase differencing: row0 = totals, rows 1..9 = thresholds
      for (int j = 0; j < 10; ++j) {
        double cn = C[j] - (j < 9 ? C[j + 1] : 0.0);
        double ac = A[j] - (j < 9 ? A[j + 1] : 0.0);
        double cf = T[j] - (j < 9 ? T[j + 1] : 0.0);
        if (cn > 0.0) e += fabs(cf / cn - ac / cn) * (cn / (double)n);
      }
    } else {
      for (int j = 0; j < nb; ++j) {
        double cn = C[j];
        if (cn > 0.0) e += fabs(T[j] / cn - A[j] / cn) * (cn / (double)n);
      }
    }
    out[0] = (float)e;
  }
}

extern "C" void kernel_launch(void* const* d_in, const int* in_sizes, int n_in,
                              void* d_out, int out_size, void* d_ws, size_t ws_size,
                              hipStream_t stream) {
  const float* conf = (const float*)d_in[0];
  const int*   pred = (const int*)d_in[1];
  const int*   lab  = (const int*)d_in[2];
  const int*   nbp  = (const int*)d_in[3];
  const int n = in_sizes[0];

  size_t per = ws_size / 3;
  int cap = (int)(per / ((size_t)NBLK * sizeof(float)));
  if (cap > MAXB) cap = MAXB;
  float* ws_cnt  = (float*)d_ws;
  float* ws_acc  = (float*)((char*)d_ws + (size_t)cap * NBLK * sizeof(float));
  float* ws_conf = (float*)((char*)d_ws + 2ull * (size_t)cap * NBLK * sizeof(float));

  ece_partial<<<NBLK, TPB, 0, stream>>>(conf, pred, lab, nbp, n, cap, ws_cnt, ws_acc, ws_conf);
  ece_final<<<1, 640, 0, stream>>>(ws_cnt, ws_acc, ws_conf, nbp, n, cap, (float*)d_out);
}